// Round 6
// baseline (436.620 us; speedup 1.0000x reference)
//
#include <hip/hip_runtime.h>
#include <stdint.h>

typedef __bf16          bf16x8  __attribute__((ext_vector_type(8)));
typedef unsigned short  ushort8 __attribute__((ext_vector_type(8)));
typedef float           f32x4   __attribute__((ext_vector_type(4)));
typedef unsigned int    u32x2   __attribute__((ext_vector_type(2)));

__device__ __forceinline__ unsigned short f2bf(float f) {
    unsigned int u = __float_as_uint(f);
    return (unsigned short)((u + 0x7FFFu + ((u >> 16) & 1u)) >> 16);
}
__device__ __forceinline__ unsigned int pk2(float lo, float hi) {
    return ((unsigned int)f2bf(hi) << 16) | (unsigned int)f2bf(lo);
}

#define W1_SLOTS (12*16*64)
#define W2_SLOTS (8*16*64)

// Repack w1 (384x256) / w2 (256x256) fp32 -> bf16 MFMA A-operand fragments,
// natural k-order: slot (s,t,l), elem j = w[k = s*32 + (l>>4)*8 + j][n = t*16 + (l&15)].
__global__ void prep_weights(const float* __restrict__ w1, const float* __restrict__ w2,
                             unsigned short* __restrict__ w1f, unsigned short* __restrict__ w2f) {
    int id = blockIdx.x * 256 + threadIdx.x;
    if (id >= W1_SLOTS + W2_SLOTS) return;
    const float* src; unsigned short* dst; int slot;
    if (id < W1_SLOTS) { src = w1; dst = w1f; slot = id; }
    else               { src = w2; dst = w2f; slot = id - W1_SLOTS; }
    int l  = slot & 63;
    int t  = (slot >> 6) & 15;
    int s  = slot >> 10;
    int k0 = s*32 + ((l >> 4) << 3);
    int n  = t*16 + (l & 15);
    unsigned short* d = dst + (size_t)slot * 8;
    #pragma unroll
    for (int j = 0; j < 8; ++j) d[j] = f2bf(src[(size_t)(k0 + j) * 256 + n]);
}

// Persistent-block design: grid = 256 (one block per CU), 512 threads = 8 waves.
// Wave w owns output features [32w, 32w+32) of BOTH layers. Layer-1 weight
// slice (24 frags = 96 VGPR) is loaded ONCE and stays register-resident across
// all 16 row-iterations -> zero weight re-streaming (the r2/r4 latency killer).
// Per iter: produce h0 embeddings into LDS (shared by all waves), layer-1 MFMA,
// h1 cross-wave exchange via slot-layout LDS (r4-validated math, 32-feat form),
// layer-2 MFMA (weight slice reloaded per iter, 64 transient VGPR), store.
// Only __syncthreads (2/iter) -- no inline-asm sync, no race surface.
__global__ __launch_bounds__(512, 2) void courier_main(
    const float* __restrict__ xy,   const float* __restrict__ tin,
    const float* __restrict__ w_sx, const float* __restrict__ b_sx,
    const float* __restrict__ w_cx, const float* __restrict__ b_cx,
    const float* __restrict__ w_sy, const float* __restrict__ b_sy,
    const float* __restrict__ w_cy, const float* __restrict__ b_cy,
    const float* __restrict__ w_t,  const float* __restrict__ b_t,
    const unsigned short* __restrict__ w1f, const float* __restrict__ b1,
    const unsigned short* __restrict__ w2f, const float* __restrict__ b2,
    float* __restrict__ out)
{
    __shared__ __align__(16) unsigned short h0s[12*4*64*8];   // 48 KB [s][mi][lane'][8]
    __shared__ __align__(16) unsigned short h1s[ 8*4*64*8];   // 32 KB [s][mi][lane'][8]

    const int tid  = threadIdx.x;
    const int lane = tid & 63;
    const int wv   = tid >> 6;       // wave 0..7: features [32wv, 32wv+32)
    const int l15  = lane & 15;
    const int lq   = lane >> 4;
    const int rowbase = blockIdx.x * 1024;

    const bf16x8* gw1 = (const bf16x8*)w1f;
    const bf16x8* gw2 = (const bf16x8*)w2f;

    // persistent layer-1 weight slice: tiles 2wv, 2wv+1 for all 12 k-steps
    bf16x8 w1r[12][2];
    #pragma unroll
    for (int s = 0; s < 12; ++s)
        #pragma unroll
        for (int tt = 0; tt < 2; ++tt)
            w1r[s][tt] = gw1[(size_t)((s*16 + 2*wv + tt)*64 + lane)];

    const f32x4 bv1[2] = { *(const f32x4*)(b1 + 32*wv +      4*lq),
                           *(const f32x4*)(b1 + 32*wv + 16 + 4*lq) };
    const f32x4 bv2[2] = { *(const f32x4*)(b2 + 32*wv +      4*lq),
                           *(const f32x4*)(b2 + 32*wv + 16 + 4*lq) };

    // software-pipelined inputs (lane = row within the 64-row tile)
    float px = xy[(size_t)(rowbase + lane)*2 + 0];
    float py = xy[(size_t)(rowbase + lane)*2 + 1];
    float pt = tin[rowbase + lane];

    #pragma unroll 1
    for (int it = 0; it < 16; ++it) {
        const int rowblk = rowbase + it*64;

        // -------- produce h0: this wave's 6 of 48 units (unit = (s, i)) --------
        #pragma unroll
        for (int uu = 0; uu < 6; ++uu) {
            const int u = wv*6 + uu;
            const int s = u >> 2;
            const int i = u & 3;
            const float* wp; const float* bp; float c; int o;
            bool iscos = false, istime = false;
            if (s < 8) {
                const int seg = s >> 1;          // 0:sinx 1:cosx 2:siny 3:cosy
                wp = (seg==0)?w_sx:(seg==1)?w_cx:(seg==2)?w_sy:w_cy;
                bp = (seg==0)?b_sx:(seg==1)?b_cx:(seg==2)?b_sy:b_cy;
                c  = (seg<2)?px:py;
                iscos = (s & 2) != 0;
                o  = (s & 1) << 5;
            } else {
                wp = w_t; bp = b_t; c = pt; istime = true;
                o  = (s - 8) << 5;
            }
            f32x4 wa = *(const f32x4*)(wp + o + 8*i);
            f32x4 wb = *(const f32x4*)(wp + o + 8*i + 4);
            f32x4 ba = *(const f32x4*)(bp + o + 8*i);
            f32x4 bb = *(const f32x4*)(bp + o + 8*i + 4);
            ushort8 uo;
            #pragma unroll
            for (int j = 0; j < 8; ++j) {
                float wvv = (j<4)?wa[j]:wb[j-4];
                float bvv = (j<4)?ba[j]:bb[j-4];
                float th = c*wvv + bvv;
                float v;
                if (istime)      v = fmaxf(th, 0.01f*th);
                else if (iscos)  v = __cosf(th);
                else             v = __sinf(th);
                uo[j] = f2bf(v);
            }
            // row = lane: slot (s, mi=row>>4), lane' = i*16 + (row&15)
            *(bf16x8*)&h0s[ ((s*4 + (lane>>4))*64 + i*16 + l15) * 8 ] =
                __builtin_bit_cast(bf16x8, uo);
        }

        // prefetch next iteration's inputs (land during this iter's compute)
        if (it < 15) {
            px = xy[(size_t)(rowblk + 64 + lane)*2 + 0];
            py = xy[(size_t)(rowblk + 64 + lane)*2 + 1];
            pt = tin[rowblk + 64 + lane];
        }

        __syncthreads();                 // S1: h0 ready (also: all waves past
                                         // prev iter's layer-2 h1 reads)

        // -------- layer 1: register-resident weights --------
        f32x4 acc[2][4];
        #pragma unroll
        for (int a=0;a<2;++a)
          #pragma unroll
          for (int b=0;b<4;++b)
            #pragma unroll
            for (int i=0;i<4;++i) acc[a][b][i] = 0.0f;

        #pragma unroll
        for (int s = 0; s < 12; ++s) {
            bf16x8 mf[4];
            #pragma unroll
            for (int mi=0; mi<4; ++mi)
                mf[mi] = *(const bf16x8*)&h0s[ ((s*4 + mi)*64 + lane) * 8 ];
            #pragma unroll
            for (int tt=0; tt<2; ++tt)
                #pragma unroll
                for (int mi=0; mi<4; ++mi)
                    acc[tt][mi] = __builtin_amdgcn_mfma_f32_16x16x32_bf16(
                                      w1r[s][tt], mf[mi], acc[tt][mi], 0,0,0);
        }

        // -------- epilogue 1: h1 -> slot LDS (32-feat wave form) --------
        // f = 32wv+16tt+4lq+r -> slot wv, lane' = (2tt+(lq>>1))*16+l15,
        // shorts j = 4(lq&1)+r -> one b64 write per (tt,mi)
        #pragma unroll
        for (int tt=0; tt<2; ++tt) {
            const int lphi = 2*tt + (lq >> 1);
            #pragma unroll
            for (int mi=0; mi<4; ++mi) {
                float v0 = acc[tt][mi][0] + bv1[tt][0]; v0 = fmaxf(v0, 0.01f*v0);
                float v1 = acc[tt][mi][1] + bv1[tt][1]; v1 = fmaxf(v1, 0.01f*v1);
                float v2 = acc[tt][mi][2] + bv1[tt][2]; v2 = fmaxf(v2, 0.01f*v2);
                float v3 = acc[tt][mi][3] + bv1[tt][3]; v3 = fmaxf(v3, 0.01f*v3);
                u32x2 dd; dd[0] = pk2(v0, v1); dd[1] = pk2(v2, v3);
                unsigned int* base =
                    (unsigned int*)&h1s[ ((wv*4 + mi)*64 + lphi*16 + l15) * 8 ];
                *(u32x2*)(base + 2*(lq & 1)) = dd;
            }
        }

        __syncthreads();                 // S2: h1 ready

        // -------- layer 2: weight slice reloaded per iter (transient regs) ----
        bf16x8 w2r[8][2];
        #pragma unroll
        for (int s = 0; s < 8; ++s)
            #pragma unroll
            for (int tt = 0; tt < 2; ++tt)
                w2r[s][tt] = gw2[(size_t)((s*16 + 2*wv + tt)*64 + lane)];

        #pragma unroll
        for (int a=0;a<2;++a)
          #pragma unroll
          for (int b=0;b<4;++b)
            #pragma unroll
            for (int i=0;i<4;++i) acc[a][b][i] = 0.0f;

        #pragma unroll
        for (int s = 0; s < 8; ++s) {
            bf16x8 mf[4];
            #pragma unroll
            for (int mi=0; mi<4; ++mi)
                mf[mi] = *(const bf16x8*)&h1s[ ((s*4 + mi)*64 + lane) * 8 ];
            #pragma unroll
            for (int tt=0; tt<2; ++tt)
                #pragma unroll
                for (int mi=0; mi<4; ++mi)
                    acc[tt][mi] = __builtin_amdgcn_mfma_f32_16x16x32_bf16(
                                      w2r[s][tt], mf[mi], acc[tt][mi], 0,0,0);
        }

        // -------- epilogue 2: out = leaky(acc + b2) --------
        #pragma unroll
        for (int tt=0; tt<2; ++tt) {
            #pragma unroll
            for (int mi=0; mi<4; ++mi) {
                f32x4 o;
                #pragma unroll
                for (int r=0; r<4; ++r) {
                    float v = acc[tt][mi][r] + bv2[tt][r];
                    o[r] = fmaxf(v, 0.01f*v);
                }
                const int row = rowblk + 16*mi + l15;
                *(f32x4*)(out + (size_t)row*256 + 32*wv + 16*tt + 4*lq) = o;
            }
        }
    }
}

extern "C" void kernel_launch(void* const* d_in, const int* in_sizes, int n_in,
                              void* d_out, int out_size, void* d_ws, size_t ws_size,
                              hipStream_t stream) {
    const float* xy   = (const float*)d_in[0];
    const float* tin  = (const float*)d_in[1];
    const float* w_sx = (const float*)d_in[2];
    const float* b_sx = (const float*)d_in[3];
    const float* w_cx = (const float*)d_in[4];
    const float* b_cx = (const float*)d_in[5];
    const float* w_sy = (const float*)d_in[6];
    const float* b_sy = (const float*)d_in[7];
    const float* w_cy = (const float*)d_in[8];
    const float* b_cy = (const float*)d_in[9];
    const float* w_t  = (const float*)d_in[10];
    const float* b_t  = (const float*)d_in[11];
    const float* w1   = (const float*)d_in[12];
    const float* b1   = (const float*)d_in[13];
    const float* w2   = (const float*)d_in[14];
    const float* b2   = (const float*)d_in[15];

    unsigned short* w1f = (unsigned short*)d_ws;        // 196608 B
    unsigned short* w2f = w1f + (size_t)W1_SLOTS * 8;   // 131072 B

    prep_weights<<<(W1_SLOTS + W2_SLOTS + 255)/256, 256, 0, stream>>>(w1, w2, w1f, w2f);
    courier_main<<<256, 512, 0, stream>>>(xy, tin, w_sx,b_sx,w_cx,b_cx,
                                          w_sy,b_sy,w_cy,b_cy,w_t,b_t,
                                          w1f, b1, w2f, b2, (float*)d_out);
}

// Round 7
// 434.181 us; speedup vs baseline: 1.0056x; 1.0056x over previous
//
#include <hip/hip_runtime.h>
#include <stdint.h>

typedef __bf16          bf16x8  __attribute__((ext_vector_type(8)));
typedef unsigned short  ushort8 __attribute__((ext_vector_type(8)));
typedef float           f32x4   __attribute__((ext_vector_type(4)));
typedef unsigned int    u32x2   __attribute__((ext_vector_type(2)));

__device__ __forceinline__ unsigned short f2bf(float f) {
    unsigned int u = __float_as_uint(f);
    return (unsigned short)((u + 0x7FFFu + ((u >> 16) & 1u)) >> 16);
}
__device__ __forceinline__ unsigned int pk2(float lo, float hi) {
    return ((unsigned int)f2bf(hi) << 16) | (unsigned int)f2bf(lo);
}

#define W1_SLOTS (12*16*64)
#define W2_SLOTS (8*16*64)

// Repack w1 (384x256) / w2 (256x256) fp32 -> bf16 MFMA A-operand fragments,
// natural k-order: slot (s,t,l), elem j = w[k = s*32 + (l>>4)*8 + j][n = t*16 + (l&15)].
__global__ void prep_weights(const float* __restrict__ w1, const float* __restrict__ w2,
                             unsigned short* __restrict__ w1f, unsigned short* __restrict__ w2f) {
    int id = blockIdx.x * 256 + threadIdx.x;
    if (id >= W1_SLOTS + W2_SLOTS) return;
    const float* src; unsigned short* dst; int slot;
    if (id < W1_SLOTS) { src = w1; dst = w1f; slot = id; }
    else               { src = w2; dst = w2f; slot = id - W1_SLOTS; }
    int l  = slot & 63;
    int t  = (slot >> 6) & 15;
    int s  = slot >> 10;
    int k0 = s*32 + ((l >> 4) << 3);
    int n  = t*16 + (l & 15);
    unsigned short* d = dst + (size_t)slot * 8;
    #pragma unroll
    for (int j = 0; j < 8; ++j) d[j] = f2bf(src[(size_t)(k0 + j) * 256 + n]);
}

// Persistent-block design: grid = 256 (one block per CU), 512 threads = 8 waves,
// 2 waves/SIMD -> 256-VGPR budget (launch_bounds(512), NO second arg: r6's
// (512,2) capped the allocator at 128 and spilled everything -> 54MB scratch).
// Wave w owns output features [32w,32w+32) of BOTH layers; w1 slice (96 VGPR)
// AND w2 slice (64 VGPR) register-resident, loaded ONCE -> zero weight memory
// traffic in the row loop. Per iter: h0 embeddings -> LDS (shared), layer-1
// MFMA, h1 cross-wave slot exchange (r4-validated), layer-2 MFMA, f32x4 store.
// 2 __syncthreads/iter, no inline-asm sync.
__global__ __launch_bounds__(512) void courier_main(
    const float* __restrict__ xy,   const float* __restrict__ tin,
    const float* __restrict__ w_sx, const float* __restrict__ b_sx,
    const float* __restrict__ w_cx, const float* __restrict__ b_cx,
    const float* __restrict__ w_sy, const float* __restrict__ b_sy,
    const float* __restrict__ w_cy, const float* __restrict__ b_cy,
    const float* __restrict__ w_t,  const float* __restrict__ b_t,
    const unsigned short* __restrict__ w1f, const float* __restrict__ b1,
    const unsigned short* __restrict__ w2f, const float* __restrict__ b2,
    float* __restrict__ out)
{
    __shared__ __align__(16) unsigned short h0s[12*4*64*8];   // 48 KB [s][mi][lane'][8]
    __shared__ __align__(16) unsigned short h1s[ 8*4*64*8];   // 32 KB [s][mi][lane'][8]

    const int tid  = threadIdx.x;
    const int lane = tid & 63;
    const int wv   = tid >> 6;       // wave 0..7: features [32wv, 32wv+32)
    const int l15  = lane & 15;
    const int lq   = lane >> 4;
    const int rowbase = blockIdx.x * 1024;

    const bf16x8* gw1 = (const bf16x8*)w1f;
    const bf16x8* gw2 = (const bf16x8*)w2f;

    // persistent weight slices: loaded once, live across all 16 iterations
    bf16x8 w1r[12][2];
    #pragma unroll
    for (int s = 0; s < 12; ++s)
        #pragma unroll
        for (int tt = 0; tt < 2; ++tt)
            w1r[s][tt] = gw1[(size_t)((s*16 + 2*wv + tt)*64 + lane)];
    bf16x8 w2r[8][2];
    #pragma unroll
    for (int s = 0; s < 8; ++s)
        #pragma unroll
        for (int tt = 0; tt < 2; ++tt)
            w2r[s][tt] = gw2[(size_t)((s*16 + 2*wv + tt)*64 + lane)];

    const f32x4 bv1[2] = { *(const f32x4*)(b1 + 32*wv +      4*lq),
                           *(const f32x4*)(b1 + 32*wv + 16 + 4*lq) };
    const f32x4 bv2[2] = { *(const f32x4*)(b2 + 32*wv +      4*lq),
                           *(const f32x4*)(b2 + 32*wv + 16 + 4*lq) };

    // software-pipelined inputs (lane = row within the 64-row tile)
    float px = xy[(size_t)(rowbase + lane)*2 + 0];
    float py = xy[(size_t)(rowbase + lane)*2 + 1];
    float pt = tin[rowbase + lane];

    #pragma unroll 1
    for (int it = 0; it < 16; ++it) {
        const int rowblk = rowbase + it*64;

        // -------- produce h0: this wave's 6 of 48 units (unit = (s, i)) --------
        #pragma unroll
        for (int uu = 0; uu < 6; ++uu) {
            const int u = wv*6 + uu;
            const int s = u >> 2;
            const int i = u & 3;
            const float* wp; const float* bp; float c; int o;
            bool iscos = false, istime = false;
            if (s < 8) {
                const int seg = s >> 1;          // 0:sinx 1:cosx 2:siny 3:cosy
                wp = (seg==0)?w_sx:(seg==1)?w_cx:(seg==2)?w_sy:w_cy;
                bp = (seg==0)?b_sx:(seg==1)?b_cx:(seg==2)?b_sy:b_cy;
                c  = (seg<2)?px:py;
                iscos = (s & 2) != 0;
                o  = (s & 1) << 5;
            } else {
                wp = w_t; bp = b_t; c = pt; istime = true;
                o  = (s - 8) << 5;
            }
            f32x4 wa = *(const f32x4*)(wp + o + 8*i);
            f32x4 wb = *(const f32x4*)(wp + o + 8*i + 4);
            f32x4 ba = *(const f32x4*)(bp + o + 8*i);
            f32x4 bb = *(const f32x4*)(bp + o + 8*i + 4);
            ushort8 uo;
            #pragma unroll
            for (int j = 0; j < 8; ++j) {
                float wvv = (j<4)?wa[j]:wb[j-4];
                float bvv = (j<4)?ba[j]:bb[j-4];
                float th = c*wvv + bvv;
                float v;
                if (istime)      v = fmaxf(th, 0.01f*th);
                else if (iscos)  v = __cosf(th);
                else             v = __sinf(th);
                uo[j] = f2bf(v);
            }
            // row = lane: slot (s, mi=row>>4), lane' = i*16 + (row&15)
            *(bf16x8*)&h0s[ ((s*4 + (lane>>4))*64 + i*16 + l15) * 8 ] =
                __builtin_bit_cast(bf16x8, uo);
        }

        // prefetch next iteration's inputs (land during this iter's compute)
        if (it < 15) {
            px = xy[(size_t)(rowblk + 64 + lane)*2 + 0];
            py = xy[(size_t)(rowblk + 64 + lane)*2 + 1];
            pt = tin[rowblk + 64 + lane];
        }

        __syncthreads();                 // S1: h0 ready (also: all waves past
                                         // prev iter's layer-2 h1 reads)

        // -------- layer 1: register-resident weights --------
        f32x4 acc[2][4];
        #pragma unroll
        for (int a=0;a<2;++a)
          #pragma unroll
          for (int b=0;b<4;++b)
            #pragma unroll
            for (int i=0;i<4;++i) acc[a][b][i] = 0.0f;

        #pragma unroll
        for (int s = 0; s < 12; ++s) {
            bf16x8 mf[4];
            #pragma unroll
            for (int mi=0; mi<4; ++mi)
                mf[mi] = *(const bf16x8*)&h0s[ ((s*4 + mi)*64 + lane) * 8 ];
            #pragma unroll
            for (int tt=0; tt<2; ++tt)
                #pragma unroll
                for (int mi=0; mi<4; ++mi)
                    acc[tt][mi] = __builtin_amdgcn_mfma_f32_16x16x32_bf16(
                                      w1r[s][tt], mf[mi], acc[tt][mi], 0,0,0);
        }

        // -------- epilogue 1: h1 -> slot LDS (32-feat wave form, r4-validated) --
        #pragma unroll
        for (int tt=0; tt<2; ++tt) {
            const int lphi = 2*tt + (lq >> 1);
            #pragma unroll
            for (int mi=0; mi<4; ++mi) {
                float v0 = acc[tt][mi][0] + bv1[tt][0]; v0 = fmaxf(v0, 0.01f*v0);
                float v1 = acc[tt][mi][1] + bv1[tt][1]; v1 = fmaxf(v1, 0.01f*v1);
                float v2 = acc[tt][mi][2] + bv1[tt][2]; v2 = fmaxf(v2, 0.01f*v2);
                float v3 = acc[tt][mi][3] + bv1[tt][3]; v3 = fmaxf(v3, 0.01f*v3);
                u32x2 dd; dd[0] = pk2(v0, v1); dd[1] = pk2(v2, v3);
                unsigned int* base =
                    (unsigned int*)&h1s[ ((wv*4 + mi)*64 + lphi*16 + l15) * 8 ];
                *(u32x2*)(base + 2*(lq & 1)) = dd;
            }
        }

        __syncthreads();                 // S2: h1 ready

        // -------- layer 2: register-resident weights --------
        #pragma unroll
        for (int a=0;a<2;++a)
          #pragma unroll
          for (int b=0;b<4;++b)
            #pragma unroll
            for (int i=0;i<4;++i) acc[a][b][i] = 0.0f;

        #pragma unroll
        for (int s = 0; s < 8; ++s) {
            bf16x8 mf[4];
            #pragma unroll
            for (int mi=0; mi<4; ++mi)
                mf[mi] = *(const bf16x8*)&h1s[ ((s*4 + mi)*64 + lane) * 8 ];
            #pragma unroll
            for (int tt=0; tt<2; ++tt)
                #pragma unroll
                for (int mi=0; mi<4; ++mi)
                    acc[tt][mi] = __builtin_amdgcn_mfma_f32_16x16x32_bf16(
                                      w2r[s][tt], mf[mi], acc[tt][mi], 0,0,0);
        }

        // -------- epilogue 2: out = leaky(acc + b2) --------
        #pragma unroll
        for (int tt=0; tt<2; ++tt) {
            #pragma unroll
            for (int mi=0; mi<4; ++mi) {
                f32x4 o;
                #pragma unroll
                for (int r=0; r<4; ++r) {
                    float v = acc[tt][mi][r] + bv2[tt][r];
                    o[r] = fmaxf(v, 0.01f*v);
                }
                const int row = rowblk + 16*mi + l15;
                *(f32x4*)(out + (size_t)row*256 + 32*wv + 16*tt + 4*lq) = o;
            }
        }
    }
}

extern "C" void kernel_launch(void* const* d_in, const int* in_sizes, int n_in,
                              void* d_out, int out_size, void* d_ws, size_t ws_size,
                              hipStream_t stream) {
    const float* xy   = (const float*)d_in[0];
    const float* tin  = (const float*)d_in[1];
    const float* w_sx = (const float*)d_in[2];
    const float* b_sx = (const float*)d_in[3];
    const float* w_cx = (const float*)d_in[4];
    const float* b_cx = (const float*)d_in[5];
    const float* w_sy = (const float*)d_in[6];
    const float* b_sy = (const float*)d_in[7];
    const float* w_cy = (const float*)d_in[8];
    const float* b_cy = (const float*)d_in[9];
    const float* w_t  = (const float*)d_in[10];
    const float* b_t  = (const float*)d_in[11];
    const float* w1   = (const float*)d_in[12];
    const float* b1   = (const float*)d_in[13];
    const float* w2   = (const float*)d_in[14];
    const float* b2   = (const float*)d_in[15];

    unsigned short* w1f = (unsigned short*)d_ws;        // 196608 B
    unsigned short* w2f = w1f + (size_t)W1_SLOTS * 8;   // 131072 B

    prep_weights<<<(W1_SLOTS + W2_SLOTS + 255)/256, 256, 0, stream>>>(w1, w2, w1f, w2f);
    courier_main<<<256, 512, 0, stream>>>(xy, tin, w_sx,b_sx,w_cx,b_cx,
                                          w_sy,b_sy,w_cy,b_cy,w_t,b_t,
                                          w1f, b1, w2f, b2, (float*)d_out);
}